// Round 11
// baseline (269.891 us; speedup 1.0000x reference)
//
#include <hip/hip_runtime.h>
#include <stdint.h>
#include <math.h>

// ---------------------------------------------------------------------------
// HardNegativeMiner round 11: r10 structure exactly (64x128 tile, 4 waves,
// acc[2][4], in-loop pinned gumbels) with __launch_bounds__(256,5):
// budget 102 regs vs measured 92 used (60 arch + 32 acc) -> 5 blocks/CU,
// 20 waves. Single-variable experiment: r10's economics + more de-phased TLP
// to fill barrier-stall VALU gaps. Recalibrated floor: gumbel VALU ~130 us
// wall (r5 standalone evidence); k_main floor ~155 us at ~95% VALUBusy.
// PRNG chain (partitionable threefry) verified bit-exact in rounds 1-10.
// ---------------------------------------------------------------------------
#define BN 16384   // batch
#define DK 256     // dim
#define NH 3276    // int(16384*0.2)
#define NJB 52     // j-strips of 64 (52*64 = 3328 >= NH)
#define NCB 128    // c-blocks of 128
#define NTILE (NJB * NCB)   // 6656 = 8 * 832

typedef __attribute__((ext_vector_type(8))) short short8;
typedef __attribute__((ext_vector_type(4))) short short4v;
typedef __attribute__((ext_vector_type(4))) float f32x4;

__host__ __device__ __forceinline__ void tf2x32(uint32_t k0, uint32_t k1,
                                                uint32_t c0, uint32_t c1,
                                                uint32_t& o0, uint32_t& o1) {
  uint32_t ks2 = 0x1BD11BDAu ^ k0 ^ k1;
  uint32_t x0 = c0 + k0, x1 = c1 + k1;
#define RR(d) { x0 += x1; x1 = (x1 << d) | (x1 >> (32 - d)); x1 ^= x0; }
  RR(13) RR(15) RR(26) RR(6)   x0 += k1;  x1 += ks2 + 1u;
  RR(17) RR(29) RR(16) RR(24)  x0 += ks2; x1 += k0  + 2u;
  RR(13) RR(15) RR(26) RR(6)   x0 += k0;  x1 += k1  + 3u;
  RR(17) RR(29) RR(16) RR(24)  x0 += k1;  x1 += ks2 + 4u;
  RR(13) RR(15) RR(26) RR(6)   x0 += ks2; x1 += k0  + 5u;
#undef RR
  o0 = x0; o1 = x1;
}

__device__ __forceinline__ uint32_t rand32_at(uint32_t k0, uint32_t k1, uint32_t p) {
  uint32_t x0, x1; tf2x32(k0, k1, 0u, p, x0, x1);
  return x0 ^ x1;
}

__device__ __forceinline__ float unif01_from_bits(uint32_t bits) {
  return __uint_as_float((bits >> 9) | 0x3f800000u) - 1.0f;
}

// gumbel at flat counter p: -log(-log(max(u, tiny))), fast v_log_f32 path
__device__ __forceinline__ float gumbel_at(uint32_t k0, uint32_t k1, uint32_t p) {
  uint32_t bits = rand32_at(k0, k1, p);
  float f = unif01_from_bits(bits);
  float u = fmaxf(f, 1.17549435e-38f);             // minval = finfo(f32).tiny
  float t = __log2f(u) * (-0.69314718055994531f);  // -ln(u) > 0
  return __log2f(t) * (-0.69314718055994531f);     // -ln(t)
}

// monotonic float->u32; pack (value, ~col): max => larger val, tie => smaller col
__device__ __forceinline__ unsigned long long packvc(float v, uint32_t c) {
  uint32_t u = __float_as_uint(v);
  u ^= ((int32_t)u < 0) ? 0xFFFFFFFFu : 0x80000000u;
  return ((unsigned long long)u << 32) | (unsigned long long)(~c);
}

// 16-byte global -> LDS async DMA. LDS dest is wave-uniform base + lane*16.
__device__ __forceinline__ void glds16(const unsigned short* g, short* l) {
  __builtin_amdgcn_global_load_lds(
      (const __attribute__((address_space(1))) void*)g,
      (__attribute__((address_space(3))) void*)l, 16, 0, 0);
}

// ---------------------------------------------------------------------------
// Fused: row inv-norm + split-bf16 copy of z*inv (GEMM acc == sim directly)
// + src_idx/best setup.
__global__ __launch_bounds__(256) void k_prep(const float* __restrict__ z,
                                              unsigned short* __restrict__ zh,
                                              unsigned short* __restrict__ zl,
                                              int* __restrict__ src_idx,
                                              unsigned long long* __restrict__ best,
                                              uint32_t k20, uint32_t k21) {
  int b = blockIdx.x, t = threadIdx.x;
  if (b < BN / 4) {
    int row = b * 4 + (t >> 6), lane = t & 63;
    float4 v = *(const float4*)&z[row * DK + lane * 4];
    float ss = v.x * v.x + v.y * v.y + v.z * v.z + v.w * v.w;
#pragma unroll
    for (int off = 32; off; off >>= 1) ss += __shfl_xor(ss, off, 64);
    float inv = 1.0f / fmaxf(sqrtf(ss), 1e-12f);
    float f[4] = {v.x * inv, v.y * inv, v.z * inv, v.w * inv};
    short4v h, l;
#pragma unroll
    for (int i = 0; i < 4; ++i) {
      uint32_t u = __float_as_uint(f[i]);
      h[i] = (short)(u >> 16);
      float r = f[i] - __uint_as_float(u & 0xFFFF0000u);
      l[i] = (short)(__float_as_uint(r) >> 16);
    }
    *(short4v*)&zh[row * DK + lane * 4] = h;
    *(short4v*)&zl[row * DK + lane * 4] = l;
  } else {
    int i = (b - BN / 4) * 256 + t;
    if (i < NH) {
      uint32_t bits = rand32_at(k20, k21, (uint32_t)i);
      src_idx[i] = (int)(bits & (uint32_t)(BN - 1));  // randint span 2^14
      best[i] = 0ull;                                 // identity for packvc keys
    }
  }
}

// ---------------------------------------------------------------------------
// 64x128 tile, 4 waves of 32x64. K=256 in 8 chunks of 32. LDS rows of 32
// shorts; 16B unit u stored at u ^ ((row>>1)&3) (2-way bank spread = free);
// DMA source addresses carry the inverse swizzle. Gumbels computed in-loop
// (4 per K-chunk, pinned) so MFMA/memory hides under gumbel VALU issue.
// (256,5): 102-reg budget vs 92 measured -> 5 blocks/CU, 20 waves.
__global__ __launch_bounds__(256, 5) void k_main(const unsigned short* __restrict__ zh,
                                                 const unsigned short* __restrict__ zl,
                                                 const int* __restrict__ src_idx,
                                                 unsigned long long* __restrict__ best,
                                                 uint32_t kt0, uint32_t kt1) {
  __shared__ __align__(16) short As_hi[64 * 32];    // 4 KB
  __shared__ __align__(16) short As_lo[64 * 32];    // 4 KB
  __shared__ __align__(16) short Bs_hi[128 * 32];   // 8 KB
  __shared__ __align__(16) short Bs_lo[128 * 32];   // 8 KB

  // XCD-aware swizzle: XCD x owns c-blocks [16x, 16x+16) -> 2 MB B-set per L2
  const int flat = blockIdx.x;                 // 6656 = 8 * (16 * 52)
  const int xcd = flat & 7, slot = flat >> 3;  // slot in [0, 832)
  const int c_base = (xcd * 16 + (slot & 15)) * 128;
  const int j_base = (slot >> 4) * 64;

  const int t = threadIdx.x;
  const int lane = t & 63, w = t >> 6;

  // staging: wave w DMAs A rows [16w,16w+16) and B rows [32w,32w+32)
  const int ra = w * 16 + (lane >> 2);           // A row
  const int rb0 = w * 32 + (lane >> 2);          // B rows rb0, rb0+16
  const int rb1 = rb0 + 16;
  const int ua = (lane & 3) ^ ((ra >> 1) & 3);   // swizzle-inverted data unit
  const int ub0 = (lane & 3) ^ ((rb0 >> 1) & 3);
  const int ub1 = (lane & 3) ^ ((rb1 >> 1) & 3);
  const uint32_t offA = (uint32_t)(src_idx[min(j_base + ra, NH - 1)] * DK + ua * 8);
  const uint32_t offB0 = (uint32_t)((c_base + rb0) * DK + ub0 * 8);
  const uint32_t offB1 = (uint32_t)((c_base + rb1) * DK + ub1 * 8);
  short* dA  = &As_hi[w * 512];   // same offset valid for hi/lo pairs
  short* dAl = &As_lo[w * 512];
  short* dB  = &Bs_hi[w * 1024];
  short* dBl = &Bs_lo[w * 1024];

  // fragment roles: wave covers m-half mh (32 rows) x c-half ch (64 cols)
  const int mh = w >> 1, ch = w & 1;
  const int cl = lane & 15, q = lane >> 4;
  int foffA[2], foffB[4];
#pragma unroll
  for (int i = 0; i < 2; ++i) {
    int r = mh * 32 + cl + i * 16;
    foffA[i] = r * 32 + (q ^ ((r >> 1) & 3)) * 8;
  }
#pragma unroll
  for (int i = 0; i < 4; ++i) {
    int r = ch * 64 + cl + i * 16;
    foffB[i] = r * 32 + (q ^ ((r >> 1) & 3)) * 8;
  }

  // epilogue coordinates (needed for in-loop gumbel counters)
  const int q4 = q * 4;
  const int coff = c_base + ch * 64;
  const int roff = j_base + mh * 32;
  const uint32_t ccl = (uint32_t)(coff + cl);

  f32x4 acc[2][4];
#pragma unroll
  for (int mt = 0; mt < 2; ++mt)
#pragma unroll
    for (int nt = 0; nt < 4; ++nt) acc[mt][nt] = (f32x4){0.f, 0.f, 0.f, 0.f};

  float gum[32];   // gum[((mt*4+r)*4)+nt], filled 4 per K-chunk

#pragma unroll
  for (int kc = 0; kc < 8; ++kc) {
    const int ko = kc * 32;
    glds16(zh + offA + ko, dA);
    glds16(zl + offA + ko, dAl);
    glds16(zh + offB0 + ko, dB);
    glds16(zh + offB1 + ko, dB + 512);
    glds16(zl + offB0 + ko, dBl);
    glds16(zl + offB1 + ko, dBl + 512);
    __syncthreads();

    short8 bh[4], bl[4];
#pragma unroll
    for (int nt = 0; nt < 4; ++nt) {
      bh[nt] = *(const short8*)&Bs_hi[foffB[nt]];
      bl[nt] = *(const short8*)&Bs_lo[foffB[nt]];
    }
#pragma unroll
    for (int mt = 0; mt < 2; ++mt) {
      short8 ah = *(const short8*)&As_hi[foffA[mt]];
      short8 al = *(const short8*)&As_lo[foffA[mt]];
#pragma unroll
      for (int nt = 0; nt < 4; ++nt) {
        acc[mt][nt] = __builtin_amdgcn_mfma_f32_16x16x32_bf16(ah, bh[nt], acc[mt][nt], 0, 0, 0);
        acc[mt][nt] = __builtin_amdgcn_mfma_f32_16x16x32_bf16(ah, bl[nt], acc[mt][nt], 0, 0, 0);
        acc[mt][nt] = __builtin_amdgcn_mfma_f32_16x16x32_bf16(al, bh[nt], acc[mt][nt], 0, 0, 0);
      }
    }

    // ---- interleaved gumbel generation: 4 of 32 per-thread gumbels ----
    // idx = kc*4+i -> (mt,r,nt) = (idx>>4, (idx>>2)&3, idx&3). The asm pin
    // forces materialization here (prevents sinking past the barrier), so
    // this VALU chain co-issues with the MFMA/ds_read latency above.
#pragma unroll
    for (int i = 0; i < 4; ++i) {
      const int idx = kc * 4 + i;
      const int mt = idx >> 4, r = (idx >> 2) & 3, nt = idx & 3;
      int gj = roff + mt * 16 + q4 + r;
      uint32_t p = (uint32_t)gj * (uint32_t)BN + ccl + (uint32_t)(nt * 16);
      float gv = gumbel_at(kt0, kt1, p);
      asm volatile("" : "+v"(gv));
      gum[idx] = gv;
    }
    __syncthreads();
  }

  // ---- lean epilogue: tot = fmaf(sim,10,gum); argmax over wave's 64 cols ----
#pragma unroll
  for (int mt = 0; mt < 2; ++mt)
#pragma unroll
    for (int r = 0; r < 4; ++r) {
      int gj = roff + mt * 16 + q4 + r;
      int s = src_idx[min(gj, NH - 1)];
      float bv = -INFINITY; uint32_t bc = 0;
#pragma unroll
      for (int nt = 0; nt < 4; ++nt) {
        uint32_t c = ccl + (uint32_t)(nt * 16);
        float tot = fmaf(acc[mt][nt][r], 10.0f, gum[((mt * 4 + r) * 4) + nt]);
        tot = ((int)c == s) ? -INFINITY : tot;         // diagonal mask
        if (tot > bv) { bv = tot; bc = c; }
      }
      unsigned long long key = packvc(bv, bc);
#pragma unroll
      for (int off = 1; off <= 8; off <<= 1) {        // reduce over 16 cl lanes
        unsigned long long o = __shfl_xor(key, off, 64);
        if (o > key) key = o;
      }
      if (cl == 0 && gj < NH) atomicMax(&best[gj], key);
    }
}

__global__ __launch_bounds__(64) void k_out(const float* __restrict__ z,
                                            const int* __restrict__ src_idx,
                                            const unsigned long long* __restrict__ best,
                                            float* __restrict__ out,
                                            uint32_t ka0, uint32_t ka1) {
  int j = blockIdx.x;
  int lane = threadIdx.x;
  int s = src_idx[j];
  int tgt = (int)(~((uint32_t)(best[j] & 0xFFFFFFFFull)));
  uint32_t bits = rand32_at(ka0, ka1, (uint32_t)j);
  float alpha = unif01_from_bits(bits) * 0.5f;   // uniform * MIX_ALPHA
  float om = 1.0f - alpha;
  float4 a = *(const float4*)&z[s * DK + lane * 4];
  float4 b = *(const float4*)&z[tgt * DK + lane * 4];
  float4 o;
  o.x = alpha * a.x + om * b.x;
  o.y = alpha * a.y + om * b.y;
  o.z = alpha * a.z + om * b.z;
  o.w = alpha * a.w + om * b.w;
  *(float4*)&out[j * DK + lane * 4] = o;
}

// ---------------------------------------------------------------------------
extern "C" void kernel_launch(void* const* d_in, const int* in_sizes, int n_in,
                              void* d_out, int out_size, void* d_ws, size_t ws_size,
                              hipStream_t stream) {
  const float* z = (const float*)d_in[0];
  float* out = (float*)d_out;
  char* ws = (char*)d_ws;
  // ws layout (~16.8 MB):
  int*                src_idx = (int*)(ws);                        // 16 KB
  unsigned long long* best    = (unsigned long long*)(ws + 16384); // 32 KB
  unsigned short*     zh      = (unsigned short*)(ws + 65536);     // 8.39 MB
  unsigned short*     zl      = (unsigned short*)(ws + 65536 + 8388608);

  // host-side threefry key derivation (partitionable scheme, verified round 1)
  uint32_t r0 = 0u, r1 = 42u;
  uint32_t ks0, ks1, kt0, kt1, ka0, ka1, k20, k21;
  tf2x32(r0, r1, 0u, 0u, ks0, ks1);   // k_src   = split(root,3)[0]
  tf2x32(r0, r1, 0u, 1u, kt0, kt1);   // k_tgt   = split(root,3)[1]
  tf2x32(r0, r1, 0u, 2u, ka0, ka1);   // k_alpha = split(root,3)[2]
  tf2x32(ks0, ks1, 0u, 1u, k20, k21); // split(k_src,2)[1] (randint lower bits)

  k_prep<<<dim3(BN / 4 + (NH + 255) / 256), dim3(256), 0, stream>>>(
      z, zh, zl, src_idx, best, k20, k21);
  k_main<<<dim3(NTILE), dim3(256), 0, stream>>>(zh, zl, src_idx, best, kt0, kt1);
  k_out <<<dim3(NH), dim3(64), 0, stream>>>(z, src_idx, best, out, ka0, ka1);
}

// Round 12
// 245.679 us; speedup vs baseline: 1.0985x; 1.0985x over previous
//
#include <hip/hip_runtime.h>
#include <stdint.h>
#include <math.h>

// ---------------------------------------------------------------------------
// HardNegativeMiner round 12: r10 base (64x128 tile, 4 waves, acc[2][4],
// in-loop pinned gumbels, (256,4) -> 4 blocks/CU) + split-barrier pipelined
// K-loop: barrier1 (DMA landed) -> ds_read frags -> barrier2 (LDS free) ->
// issue next chunk's DMA -> MFMA+gumbel. The next barrier1 then waits on
// DMAs issued a full compute phase (~600 cyc) earlier -> ~zero exposed L2
// latency, same LDS (24 KB single buffer), same registers.
// r11 lesson: live regs = 60 arch + 32 acc + 32 gum ~ 124 -> only (256,4)
// fits; (256,5) spilled (WRITE 179 MB).
// PRNG chain (partitionable threefry) verified bit-exact in rounds 1-11.
// ---------------------------------------------------------------------------
#define BN 16384   // batch
#define DK 256     // dim
#define NH 3276    // int(16384*0.2)
#define NJB 52     // j-strips of 64 (52*64 = 3328 >= NH)
#define NCB 128    // c-blocks of 128
#define NTILE (NJB * NCB)   // 6656 = 8 * 832

typedef __attribute__((ext_vector_type(8))) short short8;
typedef __attribute__((ext_vector_type(4))) short short4v;
typedef __attribute__((ext_vector_type(4))) float f32x4;

__host__ __device__ __forceinline__ void tf2x32(uint32_t k0, uint32_t k1,
                                                uint32_t c0, uint32_t c1,
                                                uint32_t& o0, uint32_t& o1) {
  uint32_t ks2 = 0x1BD11BDAu ^ k0 ^ k1;
  uint32_t x0 = c0 + k0, x1 = c1 + k1;
#define RR(d) { x0 += x1; x1 = (x1 << d) | (x1 >> (32 - d)); x1 ^= x0; }
  RR(13) RR(15) RR(26) RR(6)   x0 += k1;  x1 += ks2 + 1u;
  RR(17) RR(29) RR(16) RR(24)  x0 += ks2; x1 += k0  + 2u;
  RR(13) RR(15) RR(26) RR(6)   x0 += k0;  x1 += k1  + 3u;
  RR(17) RR(29) RR(16) RR(24)  x0 += k1;  x1 += ks2 + 4u;
  RR(13) RR(15) RR(26) RR(6)   x0 += ks2; x1 += k0  + 5u;
#undef RR
  o0 = x0; o1 = x1;
}

__device__ __forceinline__ uint32_t rand32_at(uint32_t k0, uint32_t k1, uint32_t p) {
  uint32_t x0, x1; tf2x32(k0, k1, 0u, p, x0, x1);
  return x0 ^ x1;
}

__device__ __forceinline__ float unif01_from_bits(uint32_t bits) {
  return __uint_as_float((bits >> 9) | 0x3f800000u) - 1.0f;
}

// gumbel at flat counter p: -log(-log(max(u, tiny))), fast v_log_f32 path
__device__ __forceinline__ float gumbel_at(uint32_t k0, uint32_t k1, uint32_t p) {
  uint32_t bits = rand32_at(k0, k1, p);
  float f = unif01_from_bits(bits);
  float u = fmaxf(f, 1.17549435e-38f);             // minval = finfo(f32).tiny
  float t = __log2f(u) * (-0.69314718055994531f);  // -ln(u) > 0
  return __log2f(t) * (-0.69314718055994531f);     // -ln(t)
}

// monotonic float->u32; pack (value, ~col): max => larger val, tie => smaller col
__device__ __forceinline__ unsigned long long packvc(float v, uint32_t c) {
  uint32_t u = __float_as_uint(v);
  u ^= ((int32_t)u < 0) ? 0xFFFFFFFFu : 0x80000000u;
  return ((unsigned long long)u << 32) | (unsigned long long)(~c);
}

// 16-byte global -> LDS async DMA. LDS dest is wave-uniform base + lane*16.
__device__ __forceinline__ void glds16(const unsigned short* g, short* l) {
  __builtin_amdgcn_global_load_lds(
      (const __attribute__((address_space(1))) void*)g,
      (__attribute__((address_space(3))) void*)l, 16, 0, 0);
}

// ---------------------------------------------------------------------------
// Fused: row inv-norm + split-bf16 copy of z*inv (GEMM acc == sim directly)
// + src_idx/best setup.
__global__ __launch_bounds__(256) void k_prep(const float* __restrict__ z,
                                              unsigned short* __restrict__ zh,
                                              unsigned short* __restrict__ zl,
                                              int* __restrict__ src_idx,
                                              unsigned long long* __restrict__ best,
                                              uint32_t k20, uint32_t k21) {
  int b = blockIdx.x, t = threadIdx.x;
  if (b < BN / 4) {
    int row = b * 4 + (t >> 6), lane = t & 63;
    float4 v = *(const float4*)&z[row * DK + lane * 4];
    float ss = v.x * v.x + v.y * v.y + v.z * v.z + v.w * v.w;
#pragma unroll
    for (int off = 32; off; off >>= 1) ss += __shfl_xor(ss, off, 64);
    float inv = 1.0f / fmaxf(sqrtf(ss), 1e-12f);
    float f[4] = {v.x * inv, v.y * inv, v.z * inv, v.w * inv};
    short4v h, l;
#pragma unroll
    for (int i = 0; i < 4; ++i) {
      uint32_t u = __float_as_uint(f[i]);
      h[i] = (short)(u >> 16);
      float r = f[i] - __uint_as_float(u & 0xFFFF0000u);
      l[i] = (short)(__float_as_uint(r) >> 16);
    }
    *(short4v*)&zh[row * DK + lane * 4] = h;
    *(short4v*)&zl[row * DK + lane * 4] = l;
  } else {
    int i = (b - BN / 4) * 256 + t;
    if (i < NH) {
      uint32_t bits = rand32_at(k20, k21, (uint32_t)i);
      src_idx[i] = (int)(bits & (uint32_t)(BN - 1));  // randint span 2^14
      best[i] = 0ull;                                 // identity for packvc keys
    }
  }
}

// ---------------------------------------------------------------------------
// 64x128 tile, 4 waves of 32x64. K=256 in 8 chunks of 32, split-barrier
// pipelined (see header). LDS rows of 32 shorts; 16B unit u stored at
// u ^ ((row>>1)&3); DMA source addresses carry the inverse swizzle.
__global__ __launch_bounds__(256, 4) void k_main(const unsigned short* __restrict__ zh,
                                                 const unsigned short* __restrict__ zl,
                                                 const int* __restrict__ src_idx,
                                                 unsigned long long* __restrict__ best,
                                                 uint32_t kt0, uint32_t kt1) {
  __shared__ __align__(16) short As_hi[64 * 32];    // 4 KB
  __shared__ __align__(16) short As_lo[64 * 32];    // 4 KB
  __shared__ __align__(16) short Bs_hi[128 * 32];   // 8 KB
  __shared__ __align__(16) short Bs_lo[128 * 32];   // 8 KB

  // XCD-aware swizzle: XCD x owns c-blocks [16x, 16x+16) -> 2 MB B-set per L2
  const int flat = blockIdx.x;                 // 6656 = 8 * (16 * 52)
  const int xcd = flat & 7, slot = flat >> 3;  // slot in [0, 832)
  const int c_base = (xcd * 16 + (slot & 15)) * 128;
  const int j_base = (slot >> 4) * 64;

  const int t = threadIdx.x;
  const int lane = t & 63, w = t >> 6;

  // staging: wave w DMAs A rows [16w,16w+16) and B rows [32w,32w+32)
  const int ra = w * 16 + (lane >> 2);           // A row
  const int rb0 = w * 32 + (lane >> 2);          // B rows rb0, rb0+16
  const int rb1 = rb0 + 16;
  const int ua = (lane & 3) ^ ((ra >> 1) & 3);   // swizzle-inverted data unit
  const int ub0 = (lane & 3) ^ ((rb0 >> 1) & 3);
  const int ub1 = (lane & 3) ^ ((rb1 >> 1) & 3);
  const uint32_t offA = (uint32_t)(src_idx[min(j_base + ra, NH - 1)] * DK + ua * 8);
  const uint32_t offB0 = (uint32_t)((c_base + rb0) * DK + ub0 * 8);
  const uint32_t offB1 = (uint32_t)((c_base + rb1) * DK + ub1 * 8);
  short* dA  = &As_hi[w * 512];   // same offset valid for hi/lo pairs
  short* dAl = &As_lo[w * 512];
  short* dB  = &Bs_hi[w * 1024];
  short* dBl = &Bs_lo[w * 1024];

  // fragment roles: wave covers m-half mh (32 rows) x c-half ch (64 cols)
  const int mh = w >> 1, ch = w & 1;
  const int cl = lane & 15, q = lane >> 4;
  int foffA[2], foffB[4];
#pragma unroll
  for (int i = 0; i < 2; ++i) {
    int r = mh * 32 + cl + i * 16;
    foffA[i] = r * 32 + (q ^ ((r >> 1) & 3)) * 8;
  }
#pragma unroll
  for (int i = 0; i < 4; ++i) {
    int r = ch * 64 + cl + i * 16;
    foffB[i] = r * 32 + (q ^ ((r >> 1) & 3)) * 8;
  }

  // epilogue coordinates (needed for in-loop gumbel counters)
  const int q4 = q * 4;
  const int coff = c_base + ch * 64;
  const int roff = j_base + mh * 32;
  const uint32_t ccl = (uint32_t)(coff + cl);

  f32x4 acc[2][4];
#pragma unroll
  for (int mt = 0; mt < 2; ++mt)
#pragma unroll
    for (int nt = 0; nt < 4; ++nt) acc[mt][nt] = (f32x4){0.f, 0.f, 0.f, 0.f};

  float gum[32];   // gum[((mt*4+r)*4)+nt], filled 4 per K-chunk

  // prologue: DMA chunk 0
  glds16(zh + offA, dA);
  glds16(zl + offA, dAl);
  glds16(zh + offB0, dB);
  glds16(zh + offB1, dB + 512);
  glds16(zl + offB0, dBl);
  glds16(zl + offB1, dBl + 512);

#pragma unroll
  for (int kc = 0; kc < 8; ++kc) {
    __syncthreads();   // barrier1: chunk kc's DMA landed (issued a phase ago)

    short8 ah[2], al[2], bh[4], bl[4];
#pragma unroll
    for (int nt = 0; nt < 4; ++nt) {
      bh[nt] = *(const short8*)&Bs_hi[foffB[nt]];
      bl[nt] = *(const short8*)&Bs_lo[foffB[nt]];
    }
#pragma unroll
    for (int mt = 0; mt < 2; ++mt) {
      ah[mt] = *(const short8*)&As_hi[foffA[mt]];
      al[mt] = *(const short8*)&As_lo[foffA[mt]];
    }
    __syncthreads();   // barrier2: all waves read LDS; safe to overwrite

    if (kc < 7) {      // issue chunk kc+1's DMA; lands during MFMA+gumbel below
      const int ko = (kc + 1) * 32;
      glds16(zh + offA + ko, dA);
      glds16(zl + offA + ko, dAl);
      glds16(zh + offB0 + ko, dB);
      glds16(zh + offB1 + ko, dB + 512);
      glds16(zl + offB0 + ko, dBl);
      glds16(zl + offB1 + ko, dBl + 512);
    }

#pragma unroll
    for (int mt = 0; mt < 2; ++mt)
#pragma unroll
      for (int nt = 0; nt < 4; ++nt) {
        acc[mt][nt] = __builtin_amdgcn_mfma_f32_16x16x32_bf16(ah[mt], bh[nt], acc[mt][nt], 0, 0, 0);
        acc[mt][nt] = __builtin_amdgcn_mfma_f32_16x16x32_bf16(ah[mt], bl[nt], acc[mt][nt], 0, 0, 0);
        acc[mt][nt] = __builtin_amdgcn_mfma_f32_16x16x32_bf16(al[mt], bh[nt], acc[mt][nt], 0, 0, 0);
      }

    // ---- interleaved gumbel generation: 4 of 32 per-thread gumbels ----
    // asm pin forces materialization here so the threefry VALU chain
    // co-issues with the MFMA latency above / DMA in flight.
#pragma unroll
    for (int i = 0; i < 4; ++i) {
      const int idx = kc * 4 + i;
      const int mt = idx >> 4, r = (idx >> 2) & 3, nt = idx & 3;
      int gj = roff + mt * 16 + q4 + r;
      uint32_t p = (uint32_t)gj * (uint32_t)BN + ccl + (uint32_t)(nt * 16);
      float gv = gumbel_at(kt0, kt1, p);
      asm volatile("" : "+v"(gv));
      gum[idx] = gv;
    }
  }

  // ---- lean epilogue: tot = fmaf(sim,10,gum); argmax over wave's 64 cols ----
#pragma unroll
  for (int mt = 0; mt < 2; ++mt)
#pragma unroll
    for (int r = 0; r < 4; ++r) {
      int gj = roff + mt * 16 + q4 + r;
      int s = src_idx[min(gj, NH - 1)];
      float bv = -INFINITY; uint32_t bc = 0;
#pragma unroll
      for (int nt = 0; nt < 4; ++nt) {
        uint32_t c = ccl + (uint32_t)(nt * 16);
        float tot = fmaf(acc[mt][nt][r], 10.0f, gum[((mt * 4 + r) * 4) + nt]);
        tot = ((int)c == s) ? -INFINITY : tot;         // diagonal mask
        if (tot > bv) { bv = tot; bc = c; }
      }
      unsigned long long key = packvc(bv, bc);
#pragma unroll
      for (int off = 1; off <= 8; off <<= 1) {        // reduce over 16 cl lanes
        unsigned long long o = __shfl_xor(key, off, 64);
        if (o > key) key = o;
      }
      if (cl == 0 && gj < NH) atomicMax(&best[gj], key);
    }
}

__global__ __launch_bounds__(64) void k_out(const float* __restrict__ z,
                                            const int* __restrict__ src_idx,
                                            const unsigned long long* __restrict__ best,
                                            float* __restrict__ out,
                                            uint32_t ka0, uint32_t ka1) {
  int j = blockIdx.x;
  int lane = threadIdx.x;
  int s = src_idx[j];
  int tgt = (int)(~((uint32_t)(best[j] & 0xFFFFFFFFull)));
  uint32_t bits = rand32_at(ka0, ka1, (uint32_t)j);
  float alpha = unif01_from_bits(bits) * 0.5f;   // uniform * MIX_ALPHA
  float om = 1.0f - alpha;
  float4 a = *(const float4*)&z[s * DK + lane * 4];
  float4 b = *(const float4*)&z[tgt * DK + lane * 4];
  float4 o;
  o.x = alpha * a.x + om * b.x;
  o.y = alpha * a.y + om * b.y;
  o.z = alpha * a.z + om * b.z;
  o.w = alpha * a.w + om * b.w;
  *(float4*)&out[j * DK + lane * 4] = o;
}

// ---------------------------------------------------------------------------
extern "C" void kernel_launch(void* const* d_in, const int* in_sizes, int n_in,
                              void* d_out, int out_size, void* d_ws, size_t ws_size,
                              hipStream_t stream) {
  const float* z = (const float*)d_in[0];
  float* out = (float*)d_out;
  char* ws = (char*)d_ws;
  // ws layout (~16.8 MB):
  int*                src_idx = (int*)(ws);                        // 16 KB
  unsigned long long* best    = (unsigned long long*)(ws + 16384); // 32 KB
  unsigned short*     zh      = (unsigned short*)(ws + 65536);     // 8.39 MB
  unsigned short*     zl      = (unsigned short*)(ws + 65536 + 8388608);

  // host-side threefry key derivation (partitionable scheme, verified round 1)
  uint32_t r0 = 0u, r1 = 42u;
  uint32_t ks0, ks1, kt0, kt1, ka0, ka1, k20, k21;
  tf2x32(r0, r1, 0u, 0u, ks0, ks1);   // k_src   = split(root,3)[0]
  tf2x32(r0, r1, 0u, 1u, kt0, kt1);   // k_tgt   = split(root,3)[1]
  tf2x32(r0, r1, 0u, 2u, ka0, ka1);   // k_alpha = split(root,3)[2]
  tf2x32(ks0, ks1, 0u, 1u, k20, k21); // split(k_src,2)[1] (randint lower bits)

  k_prep<<<dim3(BN / 4 + (NH + 255) / 256), dim3(256), 0, stream>>>(
      z, zh, zl, src_idx, best, k20, k21);
  k_main<<<dim3(NTILE), dim3(256), 0, stream>>>(zh, zl, src_idx, best, kt0, kt1);
  k_out <<<dim3(NH), dim3(64), 0, stream>>>(z, src_idx, best, out, ka0, ka1);
}